// Round 2
// baseline (110.242 us; speedup 1.0000x reference)
//
#include <hip/hip_runtime.h>

// Problem: B,H,W,D = 64,32,32,64 ; K=1024 ; N = 65536
#define NPTS   65536
#define DDIM   64
#define KCODES 1024
#define QOUT_ELEMS (NPTS * DDIM)

typedef _Float16 half8    __attribute__((ext_vector_type(8)));
typedef float    floatx16 __attribute__((ext_vector_type(16)));
typedef unsigned int uint;

#define AS1 __attribute__((address_space(1)))
#define AS3 __attribute__((address_space(3)))

// ws: ehp [0,128K) chunk-major f16 | elp [128K,256K) | e2 packed pairs [256K,260K)
#define WS_EHP   0
#define WS_ELP   (128*1024)
#define WS_E2    (256*1024)

union H8U { half8 v; uint u[4]; };

static __device__ __forceinline__ void gl_lds16(const void* g, void* l) {
    __builtin_amdgcn_global_load_lds((const AS1 uint*)g, (AS3 uint*)l, 16, 0, 0);
}

// ---------------------------------------------------------------------------
// Prep: one wave per code. fp16 hi/lo split, CHUNK-MAJOR tiles:
// tile T=k>>5, chunk j=d>>3, code-in-tile c=k&31:
//   byte off = T*4096 + j*512 + c*16 + (d&7)*2
// Also packs (e2h,e2l) per code.
// ---------------------------------------------------------------------------
__global__ void eprep_kernel(const float* __restrict__ emb, char* __restrict__ ws) {
    const int tid = threadIdx.x;
    const int w = tid >> 6, d = tid & 63;
    const int k = blockIdx.x * 4 + w;
    float v = emb[(size_t)k * DDIM + d];
    _Float16 h = (_Float16)v;
    _Float16 l = (_Float16)(v - (float)h);
    size_t off = (size_t)(k >> 5) * 4096 + (size_t)(d >> 3) * 512
               + (size_t)(k & 31) * 16 + (size_t)(d & 7) * 2;
    *(_Float16*)(ws + WS_EHP + off) = h;
    *(_Float16*)(ws + WS_ELP + off) = l;
    float s = v * v;
    #pragma unroll
    for (int m = 1; m < 64; m <<= 1) s += __shfl_xor(s, m, 64);
    if (d == 0) {
        _Float16 e2h = (_Float16)s;
        _Float16 e2l = (_Float16)(s - (float)e2h);
        unsigned short hb = *(unsigned short*)&e2h;
        unsigned short lb = *(unsigned short*)&e2l;
        ((uint*)(ws + WS_E2))[k] = (uint)hb | ((uint)lb << 16);
    }
}

// ---------------------------------------------------------------------------
// Main: grid 1024, block 256 = 4 waves, 64 points per block.
// K-SPLIT inside the block: waves {0,1} -> tiles 0..15, waves {2,3} -> 16..31,
// both pairs covering the same 64 points (wave w: points pgrp*64+(w&1)*32+col).
// -> 4096 waves total = 4 waves/SIMD (was 2): real latency hiding.
// 2-PHASE pipeline, ONE barrier per tile: issue next tile's global_load_lds
// BEFORE current tile's ds_read+MFMA+argmin; __syncthreads() at loop end
// (its vmcnt drain overlaps with ~400cy of compute instead of being serial).
// Half-argmins combined via LDS; codes in half 0 < half 1, so strict < on the
// combine reproduces jnp.argmin first-min tie-break.
//
// MFMA 32x32x16 f16 layouts (verified, absmax 0):
//   A[m][k]: m=lane&31, k=(lane>>5)*8+j ; B same with n=lane&31 ;
//   C/D: col=lane&31, row=(r&3)+8*(r>>2)+4*(lane>>5)
// ---------------------------------------------------------------------------
#define MFMA(A,B,C) __builtin_amdgcn_mfma_f32_32x32x16_f16(A,B,C,0,0,0)

__global__ __launch_bounds__(256, 4) void vq_kernel(
    const float* __restrict__ z,
    const char* __restrict__ ws_c,
    const float* __restrict__ emb,
    float* __restrict__ out)
{
    const int tid   = threadIdx.x;
    const int lane  = tid & 63;
    const int w     = __builtin_amdgcn_readfirstlane(tid >> 6);
    const int col   = lane & 31;
    const int sel8  = lane >> 5;
    const int pgrp  = blockIdx.x;      // 64 points per block
    const int pair  = w >> 1;          // K-half: 0 -> tiles 0..15, 1 -> 16..31
    const int phalf = w & 1;           // point sub-group AND staging operand
    const int tbase = pair * 16;

    __shared__ char  ebuf[2][2][8192]; // [pair][dbuf][eh 4KB | el 4KB] = 32KB
    __shared__ uint  lds_e2[1024];     // 4KB packed (e2h,e2l), all codes
    __shared__ float sbest[2][64];
    __shared__ int   scode[2][64];
    __shared__ int   s_final[64];

    // ---- A fragments: a = -2 z[pt], hi/lo fp16 ----
    const int pt = pgrp * 64 + phalf * 32 + col;
    half8 ah[4], al[4];
    {
        const float* zrow = z + (size_t)pt * DDIM + sel8 * 8;
        #pragma unroll
        for (int ks = 0; ks < 4; ++ks) {
            float4 u0 = *(const float4*)(zrow + ks * 16);
            float4 u1 = *(const float4*)(zrow + ks * 16 + 4);
            float tv[8] = {u0.x, u0.y, u0.z, u0.w, u1.x, u1.y, u1.z, u1.w};
            #pragma unroll
            for (int j = 0; j < 8; ++j) {
                float a = -2.0f * tv[j];
                _Float16 hh = (_Float16)a;
                ah[ks][j] = hh;
                al[ks][j] = (_Float16)(a - (float)hh);
            }
        }
    }
    // e2-step A operand: A[m][k]=1 ONLY for k=0,1 (sel8==0 lanes). sel8==1 lanes
    // MUST be zero or e2 gets double-counted.
    half8 ahE;
    { H8U t0; t0.u[0] = (sel8 == 0) ? 0x3C003C00u : 0u;
      t0.u[1] = t0.u[2] = t0.u[3] = 0u; ahE = t0.v; }

    const floatx16 zeroC = {};

    float best[16];
    int   bt[16];
    #pragma unroll
    for (int r = 0; r < 16; ++r) { best[r] = 3.4e38f; bt[r] = 0; }

    // stage all e2 pairs (4KB): one 1KB chunk per wave
    gl_lds16(ws_c + WS_E2 + w * 1024 + lane * 16, (char*)lds_e2 + w * 1024);

    // wave w stages 4KB/tile for ITS pair: operand phalf (0=eh, 1=el)
#define STAGE(CUR, T) do {                                                    \
    const char* _s = ws_c + (phalf ? WS_ELP : WS_EHP)                         \
                   + (size_t)(tbase + (T)) * 4096 + lane * 16;                \
    char* _d = &ebuf[pair][CUR][phalf * 4096] + lane * 16;                    \
    gl_lds16(_s,        _d);                                                  \
    gl_lds16(_s + 1024, _d + 1024);                                           \
    gl_lds16(_s + 2048, _d + 2048);                                           \
    gl_lds16(_s + 3072, _d + 3072);                                           \
} while (0)

    STAGE(0, 0);
    __syncthreads();   // prologue: tile 0 + e2 staged

    const int myoff = sel8 * 512 + col * 16;   // chunk-major frag base in tile

    for (int t = 0; t < 16; ++t) {
        const int cur = t & 1;
        if (t < 15) STAGE(cur ^ 1, t + 1);     // issue next-tile loads FIRST

        const char* bb = &ebuf[pair][cur][0] + myoff;
        half8 bh[4], bl[4];
        #pragma unroll
        for (int ks = 0; ks < 4; ++ks) {
            bh[ks] = *(const half8*)(bb + ks * 1024);
            bl[ks] = *(const half8*)(bb + 4096 + ks * 1024);
        }
        half8 bhE;
        { H8U u; u.u[0] = lds_e2[(tbase + t) * 32 + col];
          u.u[1] = u.u[2] = u.u[3] = 0u; bhE = u.v; }

        __builtin_amdgcn_s_setprio(1);
        floatx16 acc = MFMA(ah[0], bh[0], zeroC);
        acc = MFMA(ah[1], bh[1], acc);
        acc = MFMA(ah[2], bh[2], acc);
        acc = MFMA(ah[3], bh[3], acc);
        acc = MFMA(ahE,   bhE,  acc);
        acc = MFMA(ah[0], bl[0], acc);
        acc = MFMA(ah[1], bl[1], acc);
        acc = MFMA(ah[2], bl[2], acc);
        acc = MFMA(ah[3], bl[3], acc);
        acc = MFMA(al[0], bh[0], acc);
        acc = MFMA(al[1], bh[1], acc);
        acc = MFMA(al[2], bh[2], acc);
        acc = MFMA(al[3], bh[3], acc);
        __builtin_amdgcn_s_setprio(0);

        #pragma unroll
        for (int r = 0; r < 16; ++r) {
            bool c = acc[r] < best[r];     // strict <: earliest tile wins ties
            best[r] = c ? acc[r] : best[r];
            bt[r]   = c ? t      : bt[r];
        }

        if (t < 15) __syncthreads();   // staging drained; prev reads complete
    }
#undef STAGE

    // materialize codes; butterfly argmin across the 32 columns
    int code[16];
    #pragma unroll
    for (int r = 0; r < 16; ++r) code[r] = (tbase + bt[r]) * 32 + col;
    #pragma unroll
    for (int m = 1; m < 32; m <<= 1) {
        #pragma unroll
        for (int r = 0; r < 16; ++r) {
            float ov = __shfl_xor(best[r], m, 64);
            int   oc = __shfl_xor(code[r], m, 64);
            bool c = (ov < best[r]) || (ov == best[r] && oc < code[r]);
            best[r] = c ? ov : best[r];
            code[r] = c ? oc : code[r];
        }
    }
    __syncthreads();   // all tile-loop LDS traffic complete before reuse
    if (col == 0) {    // lanes 0 and 32: 16 rows each
        #pragma unroll
        for (int r = 0; r < 16; ++r) {
            int row = (r & 3) + 8 * (r >> 2) + 4 * sel8;
            sbest[pair][phalf * 32 + row] = best[r];
            scode[pair][phalf * 32 + row] = code[r];
        }
    }
    __syncthreads();

    // combine the two K-halves: strict < (half-0 codes are all smaller)
    if (tid < 64) {
        float d0 = sbest[0][tid], d1 = sbest[1][tid];
        s_final[tid] = (d1 < d0) ? scode[1][tid] : scode[0][tid];
    }
    __syncthreads();

    // indices (coalesced) + quantized gather: 64 pts x 16 float4
    if (tid < 64)
        out[QOUT_ELEMS + (size_t)pgrp * 64 + tid] = (float)s_final[tid];
    float4* outq = (float4*)out;
    const float4* emb4 = (const float4*)emb;
    #pragma unroll
    for (int it = 0; it < 4; ++it) {
        int f  = it * 256 + tid;
        int p  = f >> 4;
        int d4 = f & 15;
        int ks = s_final[p];
        outq[((size_t)pgrp * 64 + p) * (DDIM / 4) + d4] =
            emb4[(size_t)ks * (DDIM / 4) + d4];
    }
}

extern "C" void kernel_launch(void* const* d_in, const int* in_sizes, int n_in,
                              void* d_out, int out_size, void* d_ws, size_t ws_size,
                              hipStream_t stream) {
    const float* z   = (const float*)d_in[0];
    const float* emb = (const float*)d_in[1];
    float* out = (float*)d_out;
    char* ws = (char*)d_ws;

    eprep_kernel<<<KCODES / 4, 256, 0, stream>>>(emb, ws);
    vq_kernel<<<NPTS / 64, 256, 0, stream>>>(z, ws, emb, out);
}

// Round 3
// 109.581 us; speedup vs baseline: 1.0060x; 1.0060x over previous
//
#include <hip/hip_runtime.h>

// Problem: B,H,W,D = 64,32,32,64 ; K=1024 ; N = 65536
#define NPTS   65536
#define DDIM   64
#define KCODES 1024
#define QOUT_ELEMS (NPTS * DDIM)

typedef _Float16 half8    __attribute__((ext_vector_type(8)));
typedef float    floatx16 __attribute__((ext_vector_type(16)));
typedef unsigned int uint;

#define AS1 __attribute__((address_space(1)))
#define AS3 __attribute__((address_space(3)))

// ws: ehp [0,128K) chunk-major f16 | elp [128K,256K) | e2 fp32 [256K,260K)
#define WS_EHP   0
#define WS_ELP   (128*1024)
#define WS_E2    (256*1024)

static __device__ __forceinline__ void gl_lds16(const void* g, void* l) {
    __builtin_amdgcn_global_load_lds((const AS1 uint*)g, (AS3 uint*)l, 16, 0, 0);
}

// ---------------------------------------------------------------------------
// Prep: one wave per code. fp16 hi/lo split, CHUNK-MAJOR tiles:
// tile T=k>>5, chunk j=d>>3, code-in-tile c=k&31:
//   byte off = T*4096 + j*512 + c*16 + (d&7)*2
// e2 (||e||^2) stored as plain fp32 (added post-MFMA, exact).
// ---------------------------------------------------------------------------
__global__ void eprep_kernel(const float* __restrict__ emb, char* __restrict__ ws) {
    const int tid = threadIdx.x;
    const int w = tid >> 6, d = tid & 63;
    const int k = blockIdx.x * 4 + w;
    float v = emb[(size_t)k * DDIM + d];
    _Float16 h = (_Float16)v;
    _Float16 l = (_Float16)(v - (float)h);
    size_t off = (size_t)(k >> 5) * 4096 + (size_t)(d >> 3) * 512
               + (size_t)(k & 31) * 16 + (size_t)(d & 7) * 2;
    *(_Float16*)(ws + WS_EHP + off) = h;
    *(_Float16*)(ws + WS_ELP + off) = l;
    float s = v * v;
    #pragma unroll
    for (int m = 1; m < 64; m <<= 1) s += __shfl_xor(s, m, 64);
    if (d == 0) ((float*)(ws + WS_E2))[k] = s;
}

// ---------------------------------------------------------------------------
// Main: grid 1024, block 256 = 4 waves, 64 points per block.
// K-SPLIT: waves {0,1} -> tiles 0..15, waves {2,3} -> 16..31 (same 64 points).
// 2-phase pipeline, ONE barrier per tile (stage next tile first).
// Round-3 change: chain-depth attack. The per-tile MFMA work is 12 MFMAs in
// TWO INDEPENDENT 6-deep chains (was one 13-deep chain; dependent MFMA
// latency ~130cy made the chain the serial bottleneck: every pipe <25% busy
// at both 2 and 4 waves/SIMD). e2 is now a scalar fp32 add in the argmin
// merge: C/D col=lane&31 is the code index, so ||e||^2 is row-invariant
// per lane -> no MFMA needed for it.
//
// MFMA 32x32x16 f16 layouts (verified, absmax 0):
//   A[m][k]: m=lane&31, k=(lane>>5)*8+j ; B same with n=lane&31 ;
//   C/D: col=lane&31, row=(r&3)+8*(r>>2)+4*(lane>>5)
// ---------------------------------------------------------------------------
#define MFMA(A,B,C) __builtin_amdgcn_mfma_f32_32x32x16_f16(A,B,C,0,0,0)

__global__ __launch_bounds__(256, 4) void vq_kernel(
    const float* __restrict__ z,
    const char* __restrict__ ws_c,
    const float* __restrict__ emb,
    float* __restrict__ out)
{
    const int tid   = threadIdx.x;
    const int lane  = tid & 63;
    const int w     = __builtin_amdgcn_readfirstlane(tid >> 6);
    const int col   = lane & 31;
    const int sel8  = lane >> 5;
    const int pgrp  = blockIdx.x;      // 64 points per block
    const int pair  = w >> 1;          // K-half: 0 -> tiles 0..15, 1 -> 16..31
    const int phalf = w & 1;           // point sub-group AND staging operand
    const int tbase = pair * 16;

    __shared__ char  ebuf[2][2][8192]; // [pair][dbuf][eh 4KB | el 4KB] = 32KB
    __shared__ float lds_e2[1024];     // 4KB fp32 ||e||^2, all codes
    __shared__ float sbest[2][64];
    __shared__ int   scode[2][64];
    __shared__ int   s_final[64];

    // ---- A fragments: a = -2 z[pt], hi/lo fp16 ----
    const int pt = pgrp * 64 + phalf * 32 + col;
    half8 ah[4], al[4];
    {
        const float* zrow = z + (size_t)pt * DDIM + sel8 * 8;
        #pragma unroll
        for (int ks = 0; ks < 4; ++ks) {
            float4 u0 = *(const float4*)(zrow + ks * 16);
            float4 u1 = *(const float4*)(zrow + ks * 16 + 4);
            float tv[8] = {u0.x, u0.y, u0.z, u0.w, u1.x, u1.y, u1.z, u1.w};
            #pragma unroll
            for (int j = 0; j < 8; ++j) {
                float a = -2.0f * tv[j];
                _Float16 hh = (_Float16)a;
                ah[ks][j] = hh;
                al[ks][j] = (_Float16)(a - (float)hh);
            }
        }
    }

    const floatx16 zeroC = {};

    float best[16];
    int   bt[16];
    #pragma unroll
    for (int r = 0; r < 16; ++r) { best[r] = 3.4e38f; bt[r] = 0; }

    // stage all e2 fp32 (4KB): one 1KB chunk per wave
    gl_lds16(ws_c + WS_E2 + w * 1024 + lane * 16, (char*)lds_e2 + w * 1024);

    // wave w stages 4KB/tile for ITS pair: operand phalf (0=eh, 1=el)
#define STAGE(CUR, T) do {                                                    \
    const char* _s = ws_c + (phalf ? WS_ELP : WS_EHP)                         \
                   + (size_t)(tbase + (T)) * 4096 + lane * 16;                \
    char* _d = &ebuf[pair][CUR][phalf * 4096] + lane * 16;                    \
    gl_lds16(_s,        _d);                                                  \
    gl_lds16(_s + 1024, _d + 1024);                                           \
    gl_lds16(_s + 2048, _d + 2048);                                           \
    gl_lds16(_s + 3072, _d + 3072);                                           \
} while (0)

    STAGE(0, 0);
    __syncthreads();   // prologue: tile 0 + e2 staged

    const int myoff = sel8 * 512 + col * 16;   // chunk-major frag base in tile

    for (int t = 0; t < 16; ++t) {
        const int cur = t & 1;
        if (t < 15) STAGE(cur ^ 1, t + 1);     // issue next-tile loads FIRST

        const char* bb = &ebuf[pair][cur][0] + myoff;
        half8 bh[4], bl[4];
        #pragma unroll
        for (int ks = 0; ks < 4; ++ks) {
            bh[ks] = *(const half8*)(bb + ks * 1024);
            bl[ks] = *(const half8*)(bb + 4096 + ks * 1024);
        }
        float e2v = lds_e2[(tbase + t) * 32 + col];

        __builtin_amdgcn_s_setprio(1);
        // two INDEPENDENT 6-deep chains (hh x4 + lh x2 | hl x4 + lh x2)
        floatx16 c0 = MFMA(ah[0], bh[0], zeroC);
        floatx16 c1 = MFMA(ah[0], bl[0], zeroC);
        c0 = MFMA(ah[1], bh[1], c0);
        c1 = MFMA(ah[1], bl[1], c1);
        c0 = MFMA(ah[2], bh[2], c0);
        c1 = MFMA(ah[2], bl[2], c1);
        c0 = MFMA(ah[3], bh[3], c0);
        c1 = MFMA(ah[3], bl[3], c1);
        c0 = MFMA(al[0], bh[0], c0);
        c1 = MFMA(al[2], bh[2], c1);
        c0 = MFMA(al[1], bh[1], c0);
        c1 = MFMA(al[3], bh[3], c1);
        __builtin_amdgcn_s_setprio(0);

        #pragma unroll
        for (int r = 0; r < 16; ++r) {
            float d = (c0[r] + c1[r]) + e2v;
            bool c = d < best[r];          // strict <: earliest tile wins ties
            best[r] = c ? d : best[r];
            bt[r]   = c ? t : bt[r];
        }

        if (t < 15) __syncthreads();   // staging drained; prev reads complete
    }
#undef STAGE

    // materialize codes; butterfly argmin across the 32 columns
    int code[16];
    #pragma unroll
    for (int r = 0; r < 16; ++r) code[r] = (tbase + bt[r]) * 32 + col;
    #pragma unroll
    for (int m = 1; m < 32; m <<= 1) {
        #pragma unroll
        for (int r = 0; r < 16; ++r) {
            float ov = __shfl_xor(best[r], m, 64);
            int   oc = __shfl_xor(code[r], m, 64);
            bool c = (ov < best[r]) || (ov == best[r] && oc < code[r]);
            best[r] = c ? ov : best[r];
            code[r] = c ? oc : code[r];
        }
    }
    __syncthreads();   // all tile-loop LDS traffic complete before reuse
    if (col == 0) {    // lanes 0 and 32: 16 rows each
        #pragma unroll
        for (int r = 0; r < 16; ++r) {
            int row = (r & 3) + 8 * (r >> 2) + 4 * sel8;
            sbest[pair][phalf * 32 + row] = best[r];
            scode[pair][phalf * 32 + row] = code[r];
        }
    }
    __syncthreads();

    // combine the two K-halves: strict < (half-0 codes are all smaller)
    if (tid < 64) {
        float d0 = sbest[0][tid], d1 = sbest[1][tid];
        s_final[tid] = (d1 < d0) ? scode[1][tid] : scode[0][tid];
    }
    __syncthreads();

    // indices (coalesced) + quantized gather: 64 pts x 16 float4
    if (tid < 64)
        out[QOUT_ELEMS + (size_t)pgrp * 64 + tid] = (float)s_final[tid];
    float4* outq = (float4*)out;
    const float4* emb4 = (const float4*)emb;
    #pragma unroll
    for (int it = 0; it < 4; ++it) {
        int f  = it * 256 + tid;
        int p  = f >> 4;
        int d4 = f & 15;
        int ks = s_final[p];
        outq[((size_t)pgrp * 64 + p) * (DDIM / 4) + d4] =
            emb4[(size_t)ks * (DDIM / 4) + d4];
    }
}

extern "C" void kernel_launch(void* const* d_in, const int* in_sizes, int n_in,
                              void* d_out, int out_size, void* d_ws, size_t ws_size,
                              hipStream_t stream) {
    const float* z   = (const float*)d_in[0];
    const float* emb = (const float*)d_in[1];
    float* out = (float*)d_out;
    char* ws = (char*)d_ws;

    eprep_kernel<<<KCODES / 4, 256, 0, stream>>>(emb, ws);
    vq_kernel<<<NPTS / 64, 256, 0, stream>>>(z, ws, emb, out);
}

// Round 4
// 103.162 us; speedup vs baseline: 1.0686x; 1.0622x over previous
//
#include <hip/hip_runtime.h>

// Problem: B,H,W,D = 64,32,32,64 ; K=1024 ; N = 65536
#define NPTS   65536
#define DDIM   64
#define KCODES 1024
#define QOUT_ELEMS (NPTS * DDIM)

typedef _Float16 half8    __attribute__((ext_vector_type(8)));
typedef float    floatx16 __attribute__((ext_vector_type(16)));
typedef unsigned int uint;

#define AS1 __attribute__((address_space(1)))
#define AS3 __attribute__((address_space(3)))

// ws: ehp [0,128K) chunk-major f16 | elp [128K,256K) | e2 fp32 [256K,260K)
#define WS_EHP   0
#define WS_ELP   (128*1024)
#define WS_E2    (256*1024)

static __device__ __forceinline__ void gl_lds16(const void* g, void* l) {
    __builtin_amdgcn_global_load_lds((const AS1 uint*)g, (AS3 uint*)l, 16, 0, 0);
}

// ---------------------------------------------------------------------------
// Prep: one wave per code. fp16 hi/lo split, CHUNK-MAJOR tiles:
// tile T=k>>5, chunk j=d>>3, code-in-tile c=k&31:
//   byte off = T*4096 + j*512 + c*16 + (d&7)*2
// e2 (||e||^2) stored as plain fp32 (added post-MFMA, exact).
// ---------------------------------------------------------------------------
__global__ void eprep_kernel(const float* __restrict__ emb, char* __restrict__ ws) {
    const int tid = threadIdx.x;
    const int w = tid >> 6, d = tid & 63;
    const int k = blockIdx.x * 4 + w;
    float v = emb[(size_t)k * DDIM + d];
    _Float16 h = (_Float16)v;
    _Float16 l = (_Float16)(v - (float)h);
    size_t off = (size_t)(k >> 5) * 4096 + (size_t)(d >> 3) * 512
               + (size_t)(k & 31) * 16 + (size_t)(d & 7) * 2;
    *(_Float16*)(ws + WS_EHP + off) = h;
    *(_Float16*)(ws + WS_ELP + off) = l;
    float s = v * v;
    #pragma unroll
    for (int m = 1; m < 64; m <<= 1) s += __shfl_xor(s, m, 64);
    if (d == 0) ((float*)(ws + WS_E2))[k] = s;
}

// ---------------------------------------------------------------------------
// Main: grid 512, block 256 = 4 waves; wave w owns 32 points (pgrp*128+w*32+col)
// over the FULL K=1024 (32 tiles). Round-4 restructure: 3-STAGE PIPELINE so
// the DS-read, global-stage and MFMA phases of DIFFERENT tiles coexist:
//   per body: READF(t+1) [LDS->reg, independent] ; STAGE(t+2) [global->LDS,
//   into the buffer freed by reading frags(t) last iter] ; COMP(t) [MFMA on
//   regs loaded last iter -> NO lgkm wait on the critical path].
// One barrier per tile; its vmcnt/lgkm drain waits on loads issued a full
// COMP (~700cy) earlier -> never a serial stall. Explicit A/B register
// buffers via unroll-by-2 (no runtime-indexed reg arrays).
// Prior rounds showed all phase-serial structures pin at ~1800cy/wave-tile
// with every pipe <25% busy; this attacks the phase serialization itself.
//
// MFMA 32x32x16 f16 layouts (verified, absmax 0):
//   A[m][k]: m=lane&31, k=(lane>>5)*8+j ; B same with n=lane&31 ;
//   C/D: col=lane&31, row=(r&3)+8*(r>>2)+4*(lane>>5)
// ---------------------------------------------------------------------------
#define MFMA(A,B,C) __builtin_amdgcn_mfma_f32_32x32x16_f16(A,B,C,0,0,0)

__global__ __launch_bounds__(256, 2) void vq_kernel(
    const float* __restrict__ z,
    const char* __restrict__ ws_c,
    const float* __restrict__ emb,
    float* __restrict__ out)
{
    const int tid  = threadIdx.x;
    const int lane = tid & 63;
    const int w    = __builtin_amdgcn_readfirstlane(tid >> 6);
    const int col  = lane & 31;
    const int sel8 = lane >> 5;
    const int pgrp = blockIdx.x;

    __shared__ char  ebuf[2][8192];   // [dbuf][eh 4KB | el 4KB] = 16KB
    __shared__ float lds_e2[1024];    // 4KB fp32 ||e||^2, all codes
    __shared__ int   s_final[128];

    // ---- A fragments: a = -2 z[pt], hi/lo fp16 ----
    const int pt = pgrp * 128 + w * 32 + col;
    half8 ah[4], al[4];
    {
        const float* zrow = z + (size_t)pt * DDIM + sel8 * 8;
        #pragma unroll
        for (int ks = 0; ks < 4; ++ks) {
            float4 u0 = *(const float4*)(zrow + ks * 16);
            float4 u1 = *(const float4*)(zrow + ks * 16 + 4);
            float tv[8] = {u0.x, u0.y, u0.z, u0.w, u1.x, u1.y, u1.z, u1.w};
            #pragma unroll
            for (int j = 0; j < 8; ++j) {
                float a = -2.0f * tv[j];
                _Float16 hh = (_Float16)a;
                ah[ks][j] = hh;
                al[ks][j] = (_Float16)(a - (float)hh);
            }
        }
    }

    const floatx16 zeroC = {};

    float best[16];
    int   bt[16];
    #pragma unroll
    for (int r = 0; r < 16; ++r) { best[r] = 3.4e38f; bt[r] = 0; }

    // stage all e2 fp32 (4KB): one 1KB chunk per wave
    gl_lds16(ws_c + WS_E2 + w * 1024 + lane * 16, (char*)lds_e2 + w * 1024);

    // wave w stages 2KB/tile: operand = w>>1 (0=eh,1=el), half = w&1
    const int opnd = w >> 1, hsel = w & 1;
    const char* gsrc = ws_c + (opnd ? WS_ELP : WS_EHP) + hsel * 2048 + lane * 16;
    char* ld0 = &ebuf[0][0] + opnd * 4096 + hsel * 2048 + lane * 16;
    char* ld1 = &ebuf[1][0] + opnd * 4096 + hsel * 2048 + lane * 16;

#define STAGE(BUF, T) do {                                                    \
    const char* _s = gsrc + (size_t)(T) * 4096;                               \
    char* _d = (BUF) ? ld1 : ld0;                                             \
    gl_lds16(_s,        _d);                                                  \
    gl_lds16(_s + 1024, _d + 1024);                                           \
} while (0)

    const int myoff = sel8 * 512 + col * 16;   // chunk-major frag base in tile
    const char* fb0 = &ebuf[0][0] + myoff;
    const char* fb1 = &ebuf[1][0] + myoff;

#define READF(BUF, T, BH, BL, E2) do {                                        \
    const char* _b = (BUF) ? fb1 : fb0;                                       \
    _Pragma("unroll")                                                         \
    for (int ks = 0; ks < 4; ++ks) {                                          \
        BH[ks] = *(const half8*)(_b + ks * 1024);                             \
        BL[ks] = *(const half8*)(_b + 4096 + ks * 1024);                      \
    }                                                                         \
    E2 = lds_e2[(T) * 32 + col];                                              \
} while (0)

#define COMP(T, BH, BL, E2) do {                                              \
    __builtin_amdgcn_s_setprio(1);                                            \
    floatx16 c0 = MFMA(ah[0], BH[0], zeroC);                                  \
    floatx16 c1 = MFMA(ah[0], BL[0], zeroC);                                  \
    c0 = MFMA(ah[1], BH[1], c0);  c1 = MFMA(ah[1], BL[1], c1);                \
    c0 = MFMA(ah[2], BH[2], c0);  c1 = MFMA(ah[2], BL[2], c1);                \
    c0 = MFMA(ah[3], BH[3], c0);  c1 = MFMA(ah[3], BL[3], c1);                \
    c0 = MFMA(al[0], BH[0], c0);  c1 = MFMA(al[2], BH[2], c1);                \
    c0 = MFMA(al[1], BH[1], c0);  c1 = MFMA(al[3], BH[3], c1);                \
    __builtin_amdgcn_s_setprio(0);                                            \
    _Pragma("unroll")                                                         \
    for (int r = 0; r < 16; ++r) {                                            \
        float d = (c0[r] + c1[r]) + (E2);                                     \
        bool c = d < best[r];          /* strict <: earliest tile wins */     \
        best[r] = c ? d   : best[r];                                          \
        bt[r]   = c ? (T) : bt[r];                                            \
    }                                                                         \
} while (0)

    half8 bhA[4], blA[4], bhB[4], blB[4];
    float e2A, e2B;

    // prologue: buf0 <- tile0; read frags(0); issue buf1 <- tile1
    STAGE(0, 0);
    __syncthreads();                 // buf0 + e2 resident
    READF(0, 0, bhA, blA, e2A);
    STAGE(1, 1);

    for (int t = 0; t < 32; t += 2) {
        // even body: compute t (regs A), prefetch frags t+1, stage t+2
        __syncthreads();             // STAGE(t+1)->buf1 done; frags(t) drained
        READF(1, t + 1, bhB, blB, e2B);
        if (t + 2 < 32) STAGE(0, t + 2);   // buf0: frags(t) already in regs
        COMP(t, bhA, blA, e2A);

        // odd body: compute t+1 (regs B), prefetch frags t+2, stage t+3
        __syncthreads();             // STAGE(t+2)->buf0 done; frags(t+1) drained
        if (t + 2 < 32) READF(0, t + 2, bhA, blA, e2A);
        if (t + 3 < 32) STAGE(1, t + 3);   // buf1: frags(t+1) already in regs
        COMP(t + 1, bhB, blB, e2B);
    }
#undef STAGE
#undef READF
#undef COMP

    // materialize codes; butterfly argmin across the 32 columns
    int code[16];
    #pragma unroll
    for (int r = 0; r < 16; ++r) code[r] = bt[r] * 32 + col;
    #pragma unroll
    for (int m = 1; m < 32; m <<= 1) {
        #pragma unroll
        for (int r = 0; r < 16; ++r) {
            float ov = __shfl_xor(best[r], m, 64);
            int   oc = __shfl_xor(code[r], m, 64);
            bool c = (ov < best[r]) || (ov == best[r] && oc < code[r]);
            best[r] = c ? ov : best[r];
            code[r] = c ? oc : code[r];
        }
    }
    if (col == 0) {   // lanes 0 and 32: 16 rows each
        #pragma unroll
        for (int r = 0; r < 16; ++r) {
            int row = (r & 3) + 8 * (r >> 2) + 4 * sel8;
            s_final[w * 32 + row] = code[r];
        }
    }
    __syncthreads();

    // indices (coalesced) + quantized gather: 128 pts x 16 float4
    if (tid < 128)
        out[QOUT_ELEMS + (size_t)pgrp * 128 + tid] = (float)s_final[tid];
    float4* outq = (float4*)out;
    const float4* emb4 = (const float4*)emb;
    #pragma unroll
    for (int it = 0; it < 8; ++it) {
        int f  = it * 256 + tid;
        int p  = f >> 4;
        int d4 = f & 15;
        int ks = s_final[p];
        outq[((size_t)pgrp * 128 + p) * (DDIM / 4) + d4] =
            emb4[(size_t)ks * (DDIM / 4) + d4];
    }
}

extern "C" void kernel_launch(void* const* d_in, const int* in_sizes, int n_in,
                              void* d_out, int out_size, void* d_ws, size_t ws_size,
                              hipStream_t stream) {
    const float* z   = (const float*)d_in[0];
    const float* emb = (const float*)d_in[1];
    float* out = (float*)d_out;
    char* ws = (char*)d_ws;

    eprep_kernel<<<KCODES / 4, 256, 0, stream>>>(emb, ws);
    vq_kernel<<<NPTS / 128, 256, 0, stream>>>(z, ws, emb, out);
}